// Round 18
// baseline (195.579 us; speedup 1.0000x reference)
//
#include <hip/hip_runtime.h>
#include <stdint.h>

#define STRIDE 128
#define NVOX (STRIDE * STRIDE * STRIDE)   // 2^21 voxels
#define BINVOX 512                        // voxels per bin (lin-contiguous)
#define NBIN (NVOX / BINVOX)              // 4096 bins
#define HB 256                            // build blocks (chunks)
#define HT 1024                           // threads per block
#define NSEG 16                           // scan blocks
#define SEGBINS (NBIN / NSEG)             // 256 bins per scan block
#define NTB 64                            // transpose blocks (NBIN/64 bins each)
#define CAP 1536                          // pbuf capacity (bin cnt ~800+-28)
#define LINCAP 8192                       // >= ceil(n/HB)

typedef unsigned long long u64;
typedef float nfloat4 __attribute__((ext_vector_type(4)));  // native vec for NT zero

// Order-preserving float32 -> uint32 encoding. enc(any finite float) > 0,
// so LDS slots initialized to 0 never win the max for occupied voxels.
__device__ __forceinline__ uint32_t enc_f32(float f) {
  uint32_t u = __float_as_uint(f);
  return (u & 0x80000000u) ? ~u : (u | 0x80000000u);
}
__device__ __forceinline__ float dec_f32(uint32_t e) {
  uint32_t u = (e & 0x80000000u) ? (e & 0x7fffffffu) : ~e;
  return __uint_as_float(u);
}

// EXACT count of bytes equal to 1 in a u32 (carry-free; poison/stale excluded)
__device__ __forceinline__ uint32_t cnt_eq1(uint32_t w) {
  uint32_t y = w ^ 0x01010101u;
  uint32_t z = ~(((y & 0x7F7F7F7Fu) + 0x7F7F7F7Fu) | y | 0x7F7F7F7Fu);
  return __popc(z);
}

// fallback only (cnt > CAP, statistically never): binary search stitch
__device__ __forceinline__ uint32_t src_of(uint32_t u, const uint32_t* csum,
                                           const uint32_t* offs) {
  uint32_t lo = 0, hi = HB - 1;
  #pragma unroll
  for (int it = 0; it < 8; ++it) {
    uint32_t mid = (lo + hi) >> 1;
    bool gt = csum[mid] > u;
    hi = gt ? mid : hi;
    lo = gt ? lo : mid + 1;
  }
  uint32_t prev = lo ? csum[lo - 1] : 0u;
  return offs[lo] + (u - prev);
}

__device__ __forceinline__ void nt_zero4(void* p) {
  nfloat4 z = {0.f, 0.f, 0.f, 0.f};
  __builtin_nontemporal_store(z, (nfloat4*)p);
}

// 1: FUSED hist+part (+hard-tail). Build blocks [0,HB): compute lin (kept in
//    LDS), LDS histogram, wave-shuffle scan -> loff + LDS cursors, scatter
//    pairs (block-major region, no global atomics, no lin round-trip).
//    Blocks >= HB: zero rows >= vbound (no data deps -> overlaps the build).
__global__ __launch_bounds__(HT) void k_build(
    const float* __restrict__ pos, const float* __restrict__ vs_p,
    uint8_t* __restrict__ bytemap, uint32_t* __restrict__ loff,
    uint32_t* __restrict__ pairs, uint32_t* __restrict__ sync,
    float* __restrict__ out_pos, float* __restrict__ out_feat,
    float* __restrict__ out_valid, int n, int vbound, int srow) {
  __shared__ uint32_t h[NBIN];       // 16 KB: histogram, then cursors
  __shared__ uint32_t wsum[HT / 64]; // 16 wave sums
  __shared__ uint32_t linbuf[LINCAP];// 32 KB
  int t = threadIdx.x;

  if (blockIdx.x >= HB) {  // ---- hard-tail role: rows >= vbound ----
    size_t gid = (size_t)(blockIdx.x - HB) * HT + t;
    int row = vbound + (int)(gid >> 3);
    int q = (int)(gid & 7);
    if (row >= n) return;
    if (row < srow)
      nt_zero4(((float4*)out_feat) + (size_t)row * 8 + q);
    if (q == 0) {
      out_pos[(size_t)row * 3 + 0] = 0.f;
      out_pos[(size_t)row * 3 + 1] = 0.f;
      out_pos[(size_t)row * 3 + 2] = 0.f;
      out_valid[row] = 0.f;
    }
    return;
  }

  // ---- build role ----
  int b = blockIdx.x;
  if (b == 0 && t == 0) *sync = 0u;  // consumed by k_scan (next dispatch)
  for (int k = t; k < NBIN; k += HT) h[k] = 0u;
  __syncthreads();
  int chunk = (n + HB - 1) / HB;
  int i0 = b * chunk, i1 = min(n, i0 + chunk);
  int len = i1 - i0;
  float vs = vs_p[0];
  for (int j = t; j < len; j += HT) {
    size_t i = (size_t)(i0 + j);
    float x = pos[3 * i + 0];
    float y = pos[3 * i + 1];
    float z = pos[3 * i + 2];
    int lin = (int)floorf(x / vs) + STRIDE * (int)floorf(y / vs) +
              STRIDE * STRIDE * (int)floorf(z / vs);
    linbuf[j] = (uint32_t)lin;
    bytemap[lin] = 1;
    atomicAdd(&h[lin >> 9], 1u);  // LDS atomic
  }
  __syncthreads();
  // exclusive scan over h[4096] via wave shuffles (3 barriers, not 20)
  uint32_t v0 = h[t * 4 + 0], v1 = h[t * 4 + 1], v2 = h[t * 4 + 2], v3 = h[t * 4 + 3];
  uint32_t s3 = v0 + v1 + v2 + v3;
  uint32_t inc = s3;
  #pragma unroll
  for (int d = 1; d < 64; d <<= 1) {
    uint32_t o = __shfl_up(inc, d, 64);
    if ((t & 63) >= d) inc += o;
  }
  if ((t & 63) == 63) wsum[t >> 6] = inc;
  __syncthreads();
  if (t < 16) {
    uint32_t wv = wsum[t], wi = wv;
    #pragma unroll
    for (int d = 1; d < 16; d <<= 1) {
      uint32_t o = __shfl_up(wi, d, 16);
      if (t >= d) wi += o;
    }
    wsum[t] = wi - wv;  // exclusive wave offset
  }
  __syncthreads();
  uint32_t run = wsum[t >> 6] + (inc - s3);
  uint32_t* lr = &loff[(size_t)b * NBIN + t * 4];
  uint32_t c0 = run; lr[0] = run; run += v0;
  uint32_t c1 = run; lr[1] = run; run += v1;
  uint32_t c2 = run; lr[2] = run; run += v2;
  uint32_t c3 = run; lr[3] = run;
  __syncthreads();  // all v reads done -> safe to overwrite h with cursors
  h[t * 4 + 0] = (uint32_t)i0 + c0;
  h[t * 4 + 1] = (uint32_t)i0 + c1;
  h[t * 4 + 2] = (uint32_t)i0 + c2;
  h[t * 4 + 3] = (uint32_t)i0 + c3;
  __syncthreads();
  for (int j = t; j < len; j += HT) {
    int lin = (int)linbuf[j];
    uint32_t slot = atomicAdd(&h[lin >> 9], 1u);  // LDS atomic
    pairs[slot] = ((uint32_t)(lin & (BINVOX - 1)) << 21) | (uint32_t)(i0 + j);
  }
}

// 2: FUSED occupancy scan + descriptor transpose.
//    Blocks [0,NSEG): per-bin occupied count from bytemap (==1 exact) +
//    device-scope spin barrier -> occ_base, M.
//    Blocks [NSEG, NSEG+NTB): LDS-tiled transpose loff[c][bin] ->
//    offs_T[bin][c] = i0_c + loff[c][bin], with sentinel row offs_T[NBIN][c]
//    = end of chunk c, so k_pool reads contiguous 1KB descriptor rows.
__global__ __launch_bounds__(256) void k_scan(
    const uint32_t* __restrict__ bytemap_w, const uint32_t* __restrict__ loff,
    uint32_t* __restrict__ offs_T, uint32_t* __restrict__ occ_base,
    uint32_t* __restrict__ sync, uint32_t* __restrict__ seg_tot,
    uint32_t* __restrict__ Mp, int n) {
  int t = threadIdx.x;

  if (blockIdx.x >= NSEG) {  // ---- transpose role ----
    __shared__ uint32_t tile[256][65];  // 65: bank-conflict pad
    int tb = blockIdx.x - NSEG;         // 0..NTB-1, owns bins [tb*64, tb*64+64)
    int chunk = (n + HB - 1) / HB;
    uint32_t i0 = (uint32_t)(t * chunk);  // t = chunk index c
    const uint4* lp = (const uint4*)(loff + (size_t)t * NBIN + tb * 64);
    #pragma unroll
    for (int k = 0; k < 16; ++k) {
      uint4 v = lp[k];
      tile[t][k * 4 + 0] = i0 + v.x;
      tile[t][k * 4 + 1] = i0 + v.y;
      tile[t][k * 4 + 2] = i0 + v.z;
      tile[t][k * 4 + 3] = i0 + v.w;
    }
    __syncthreads();
    for (int j = 0; j < 64; ++j) {
      int bin = tb * 64 + j;
      offs_T[(size_t)bin * HB + t] = tile[t][j];  // 1KB coalesced per row
    }
    if (tb == NTB - 1)  // sentinel row: end of each chunk
      offs_T[(size_t)NBIN * HB + t] = (uint32_t)min(n, t * chunk + chunk);
    return;
  }

  // ---- occupancy-scan role ----
  __shared__ uint32_t s[SEGBINS];
  int b = blockIdx.x;
  int bin = b * SEGBINS + t;
  const uint4* bp = (const uint4*)bytemap_w + (size_t)bin * 32;  // 512 B
  uint32_t occ = 0;
  #pragma unroll
  for (int k = 0; k < 32; ++k) {
    uint4 v = bp[k];
    occ += cnt_eq1(v.x) + cnt_eq1(v.y) + cnt_eq1(v.z) + cnt_eq1(v.w);
  }
  s[t] = occ;
  __syncthreads();
  for (int off = 1; off < SEGBINS; off <<= 1) {
    uint32_t a = (t >= off) ? s[t - off] : 0u;
    __syncthreads();
    s[t] += a;
    __syncthreads();
  }
  uint32_t excl = s[t] - occ;
  if (t == 0) {
    __hip_atomic_store(&seg_tot[b], s[SEGBINS - 1], __ATOMIC_RELEASE,
                       __HIP_MEMORY_SCOPE_AGENT);
    __hip_atomic_fetch_add(sync, 1u, __ATOMIC_ACQ_REL, __HIP_MEMORY_SCOPE_AGENT);
    while (__hip_atomic_load(sync, __ATOMIC_ACQUIRE, __HIP_MEMORY_SCOPE_AGENT) <
           (uint32_t)NSEG) {}
  }
  __syncthreads();
  uint32_t pre = 0, grand = 0;
  #pragma unroll
  for (int i = 0; i < NSEG; ++i) {
    uint32_t v = __hip_atomic_load(&seg_tot[i], __ATOMIC_ACQUIRE,
                                   __HIP_MEMORY_SCOPE_AGENT);
    if (i < b) pre += v;
    grand += v;
  }
  occ_base[bin] = pre + excl;
  if (b == 0 && t == 0) Mp[0] = grand;
}

// 3: FUSED pool + soft-tail. Pool blocks: contiguous descriptor rows from
//    offs_T, then MATERIALIZE PAIR VALUES into LDS (pbuf) -- per-segment
//    contiguous global reads at stitch time -- so the gather loop is one
//    memory hop (LDS pair -> feat row) instead of two. 8-tap float4 gather,
//    channel-rotation swizzle, LDS max-pool, contiguous output slab.
//    Tail blocks: zero rows [M, vbound) (NT feat stores).
__global__ __launch_bounds__(HT) void k_pool(
    const float* __restrict__ feat, const float* __restrict__ vs_p,
    const uint32_t* __restrict__ pairs, const uint32_t* __restrict__ offs_T,
    const uint32_t* __restrict__ occ_base, const uint8_t* __restrict__ bytemap,
    const uint32_t* __restrict__ Mp,
    float* __restrict__ out_pos, float* __restrict__ out_feat,
    float* __restrict__ out_valid, int n, int vbound) {
  __shared__ uint32_t smax[BINVOX * 32];  // 64 KB, phys idx vb*32+((ch+vb)&31)
  __shared__ u64 sbw[8];
  __shared__ uint32_t offs[HB], csum[HB];  // 2 KB
  __shared__ uint32_t pbuf[CAP];           // 6 KB: pair VALUES for this bin
  int t = threadIdx.x;

  if (blockIdx.x >= NBIN) {  // ---- soft-tail role: rows [M, vbound) ----
    size_t gid = (size_t)(blockIdx.x - NBIN) * HT + t;
    int row = (int)(gid >> 3);
    int q = (int)(gid & 7);
    if (row >= vbound) return;
    uint32_t M = Mp[0];
    if ((uint32_t)row < M) return;
    nt_zero4(((float4*)out_feat) + (size_t)row * 8 + q);
    if (q == 0) {
      out_pos[(size_t)row * 3 + 0] = 0.f;
      out_pos[(size_t)row * 3 + 1] = 0.f;
      out_pos[(size_t)row * 3 + 2] = 0.f;
      out_valid[row] = 0.f;
    }
    return;
  }

  // ---- pool role ----
  int bin = blockIdx.x;
  #pragma unroll
  for (int k = 0; k < 16; ++k) smax[t + k * HT] = 0u;
  if (t < 512) {  // waves 0..7 exactly; ballot is wave-uniform
    uint32_t occb = bytemap[(size_t)bin * BINVOX + t];
    u64 m = __ballot(occb == 1u);
    if ((t & 63) == 0) sbw[t >> 6] = m;
  }
  if (t < HB) {  // contiguous descriptor rows: offs + next-bin (i0 cancels)
    uint32_t v0 = offs_T[(size_t)bin * HB + t];
    uint32_t v1 = offs_T[(size_t)(bin + 1) * HB + t];
    offs[t] = v0;
    csum[t] = v1 - v0;
  }
  __syncthreads();
  if (t < 64) {  // wave-0 inclusive scan of csum[256]
    uint32_t c0 = csum[t * 4], c1 = csum[t * 4 + 1];
    uint32_t c2 = csum[t * 4 + 2], c3 = csum[t * 4 + 3];
    uint32_t s1 = c0 + c1, s2 = s1 + c2, s3 = s2 + c3;
    uint32_t inc = s3;
    #pragma unroll
    for (int d = 1; d < 64; d <<= 1) {
      uint32_t o = __shfl_up(inc, d, 64);
      if (t >= d) inc += o;
    }
    uint32_t base = inc - s3;
    csum[t * 4]     = base + c0;
    csum[t * 4 + 1] = base + s1;
    csum[t * 4 + 2] = base + s2;
    csum[t * 4 + 3] = base + s3;
  }
  __syncthreads();
  uint32_t cnt = csum[HB - 1];
  if (cnt == 0) return;  // block-uniform

  bool fits = (cnt <= (uint32_t)CAP);  // block-uniform
  if (fits) {
    if (t < HB) {  // copy pair VALUES (contiguous per-segment global reads)
      uint32_t beg = t ? csum[t - 1] : 0u;
      uint32_t len = csum[t] - beg;
      uint32_t o = offs[t];
      for (uint32_t j = 0; j < len; ++j) pbuf[beg + j] = pairs[o + j];
    }
    __syncthreads();
  }

  int g = t >> 3;    // point slot 0..127
  int q = t & 7;     // float4 chunk (channels q*4..q*4+3)
  const float4* f4 = (const float4*)feat;
  uint32_t last = cnt - 1;
  for (uint32_t u = (uint32_t)g; u < cnt; u += 1024) {
    uint32_t pp[8];
    #pragma unroll
    for (int k = 0; k < 8; ++k) {
      uint32_t uu = min(u + 128u * k, last);
      pp[k] = fits ? pbuf[uu] : pairs[src_of(uu, csum, offs)];
    }
    float4 vv[8];
    #pragma unroll
    for (int k = 0; k < 8; ++k)
      vv[k] = f4[(size_t)(pp[k] & 0x1FFFFFu) * 8 + q];
    #pragma unroll
    for (int k = 0; k < 8; ++k) {
      uint32_t vb = pp[k] >> 21;
      uint32_t* sb = &smax[vb * 32];
      uint32_t c = (uint32_t)q * 4 + vb;  // rotation: phys ch = (ch+vb)&31
      atomicMax(&sb[(c + 0) & 31], enc_f32(vv[k].x));
      atomicMax(&sb[(c + 1) & 31], enc_f32(vv[k].y));
      atomicMax(&sb[(c + 2) & 31], enc_f32(vv[k].z));
      atomicMax(&sb[(c + 3) & 31], enc_f32(vv[k].w));
    }
  }
  __syncthreads();

  int vb = t >> 1, half = t & 1;
  u64 w = sbw[vb >> 6];
  int bit = vb & 63;
  if ((w >> bit) & 1ull) {
    uint32_t lr = (uint32_t)__popcll(w & ((1ull << bit) - 1ull));
    for (int ww = 0; ww < (vb >> 6); ++ww) lr += (uint32_t)__popcll(sbw[ww]);
    uint32_t rank = occ_base[bin] + lr;
    float4* orow = (float4*)(out_feat + (size_t)rank * 32 + half * 16);
    const uint32_t* sb = &smax[vb * 32];
    #pragma unroll
    for (int j = 0; j < 4; ++j) {
      uint32_t c = (uint32_t)half * 16 + j * 4 + vb;  // un-rotate
      float4 o;
      o.x = dec_f32(sb[(c + 0) & 31]);
      o.y = dec_f32(sb[(c + 1) & 31]);
      o.z = dec_f32(sb[(c + 2) & 31]);
      o.w = dec_f32(sb[(c + 3) & 31]);
      orow[j] = o;
    }
    if (half == 0) {
      float vs = vs_p[0];
      int lin = bin * BINVOX + vb;
      int cx = lin & 127, cy = (lin >> 7) & 127, cz = lin >> 14;
      out_pos[(size_t)rank * 3 + 0] = ((float)cx + 0.5f) * vs;
      out_pos[(size_t)rank * 3 + 1] = ((float)cy + 0.5f) * vs;
      out_pos[(size_t)rank * 3 + 2] = ((float)cz + 0.5f) * vs;
      out_valid[rank] = 1.0f;
    }
  }
}

// 4 (out-tail fallback only): wipe the scratch region (feat rows >= srow)
__global__ void k_tail2(float4* __restrict__ dst, long long cnt4) {
  long long i = (long long)blockIdx.x * blockDim.x + threadIdx.x;
  if (i < cnt4) nt_zero4(dst + i);
}

extern "C" void kernel_launch(void* const* d_in, const int* in_sizes, int n_in,
                              void* d_out, int out_size, void* d_ws, size_t ws_size,
                              hipStream_t stream) {
  const float* pos  = (const float*)d_in[0];
  const float* feat = (const float*)d_in[1];
  const float* vs   = (const float*)d_in[2];
  int n = in_sizes[0] / 3;  // 2,000,000

  float*    out_pos   = (float*)d_out;
  uint32_t* out_feat  = (uint32_t*)(out_pos + (size_t)n * 3);
  float*    out_valid = (float*)((float*)out_feat + (size_t)n * 32);

  // vs = 1.0 in this problem -> coords 0..99 -> M <= 100^3 = 1e6 voxels.
  // (The reference's STRIDE=128 lin-packing itself requires coords < 128.)
  int vbound = n < 1000000 ? n : 1000000;

  // Scratch: pairs(n) | loff[HB][NBIN] | offs_T[(NBIN+1)][HB] | occ_base(NBIN)
  // | bytemap(NVOX B). ~18.5 MB. Prefer d_ws; else output-tail rows >= srow
  // (> vbound; pool writes rows < M <= vbound; hard-tail stops at srow;
  // k_tail2 wipes after). bytemap never assumed-zero (consumers test ==1).
  size_t scratch_u32 = (size_t)n + (size_t)HB * NBIN + (size_t)(NBIN + 1) * HB +
                       NBIN + NVOX / 4;
  size_t ws_need = 256 + scratch_u32 * 4;

  uint32_t* Mp      = (uint32_t*)d_ws;
  uint32_t* sync    = Mp + 1;
  uint32_t* seg_tot = Mp + 8;  // NSEG u32

  uint32_t* base;
  int srow;
  if (ws_size >= ws_need) {
    base = (uint32_t*)((char*)d_ws + 256);
    srow = n;
  } else {
    base = out_feat + (size_t)n * 32 - scratch_u32;
    srow = (int)(((size_t)n * 32 - scratch_u32) / 32);
  }
  uint32_t* pairs    = base;
  uint32_t* loff     = pairs + n;                    // HB*NBIN
  uint32_t* offs_T   = loff + (size_t)HB * NBIN;     // (NBIN+1)*HB
  uint32_t* occ_base = offs_T + (size_t)(NBIN + 1) * HB;  // NBIN
  uint8_t*  bytemap  = (uint8_t*)(occ_base + NBIN);  // NVOX bytes

  int hard_blocks = (int)(((size_t)(n - vbound) * 8 + HT - 1) / HT);
  k_build<<<HB + hard_blocks, HT, 0, stream>>>(
      pos, vs, bytemap, loff, pairs, sync, out_pos, (float*)out_feat,
      out_valid, n, vbound, srow);
  k_scan<<<NSEG + NTB, 256, 0, stream>>>((const uint32_t*)bytemap, loff,
                                         offs_T, occ_base, sync, seg_tot, Mp, n);
  int soft_blocks = (int)(((size_t)vbound * 8 + HT - 1) / HT);
  k_pool<<<NBIN + soft_blocks, HT, 0, stream>>>(
      feat, vs, pairs, offs_T, occ_base, bytemap, Mp,
      out_pos, (float*)out_feat, out_valid, n, vbound);
  if (srow < n) {
    long long cnt4 = ((long long)n * 32 - (long long)srow * 32) / 4;
    k_tail2<<<(int)((cnt4 + 1023) / 1024), 1024, 0, stream>>>(
        (float4*)(out_feat + (size_t)srow * 32), cnt4);
  }
}

// Round 19
// 189.335 us; speedup vs baseline: 1.0330x; 1.0330x over previous
//
#include <hip/hip_runtime.h>
#include <stdint.h>

#define STRIDE 128
#define NVOX (STRIDE * STRIDE * STRIDE)   // 2^21 voxels
#define BINVOX 512                        // voxels per bin (lin-contiguous)
#define NBIN (NVOX / BINVOX)              // 4096 bins
#define HB 256                            // build blocks (chunks)
#define HT 1024                           // threads per block
#define NSEG 16                           // scan blocks
#define SEGBINS (NBIN / NSEG)             // 256 bins per scan block
#define NTB 64                            // transpose blocks (NBIN/64 bins each)
#define CAP 1536                          // srcidx capacity (bin cnt ~800+-28)
#define LINCAP 8192                       // >= ceil(n/HB)

typedef unsigned long long u64;
typedef float nfloat4 __attribute__((ext_vector_type(4)));  // native vec for NT zero

// Order-preserving float32 -> uint32 encoding. enc(any finite float) > 0,
// so LDS slots initialized to 0 never win the max for occupied voxels.
__device__ __forceinline__ uint32_t enc_f32(float f) {
  uint32_t u = __float_as_uint(f);
  return (u & 0x80000000u) ? ~u : (u | 0x80000000u);
}
__device__ __forceinline__ float dec_f32(uint32_t e) {
  uint32_t u = (e & 0x80000000u) ? (e & 0x7fffffffu) : ~e;
  return __uint_as_float(u);
}

// EXACT count of bytes equal to 1 in a u32 (carry-free; poison/stale excluded)
__device__ __forceinline__ uint32_t cnt_eq1(uint32_t w) {
  uint32_t y = w ^ 0x01010101u;
  uint32_t z = ~(((y & 0x7F7F7F7Fu) + 0x7F7F7F7Fu) | y | 0x7F7F7F7Fu);
  return __popc(z);
}

// fallback only (cnt > CAP, statistically never): binary search stitch
__device__ __forceinline__ uint32_t src_of(uint32_t u, const uint32_t* csum,
                                           const uint32_t* offs) {
  uint32_t lo = 0, hi = HB - 1;
  #pragma unroll
  for (int it = 0; it < 8; ++it) {
    uint32_t mid = (lo + hi) >> 1;
    bool gt = csum[mid] > u;
    hi = gt ? mid : hi;
    lo = gt ? lo : mid + 1;
  }
  uint32_t prev = lo ? csum[lo - 1] : 0u;
  return offs[lo] + (u - prev);
}

__device__ __forceinline__ void nt_zero4(void* p) {
  nfloat4 z = {0.f, 0.f, 0.f, 0.f};
  __builtin_nontemporal_store(z, (nfloat4*)p);
}

// 1: FUSED hist+part (+hard-tail). Build blocks [0,HB): compute lin (kept in
//    LDS), LDS histogram, wave-shuffle scan -> loff + LDS cursors, scatter
//    pairs (block-major region, no global atomics, no lin round-trip).
//    Blocks >= HB: zero rows >= vbound (no data deps -> overlaps the build).
__global__ __launch_bounds__(HT) void k_build(
    const float* __restrict__ pos, const float* __restrict__ vs_p,
    uint8_t* __restrict__ bytemap, uint32_t* __restrict__ loff,
    uint32_t* __restrict__ pairs, uint32_t* __restrict__ sync,
    float* __restrict__ out_pos, float* __restrict__ out_feat,
    float* __restrict__ out_valid, int n, int vbound, int srow) {
  __shared__ uint32_t h[NBIN];       // 16 KB: histogram, then cursors
  __shared__ uint32_t wsum[HT / 64]; // 16 wave sums
  __shared__ uint32_t linbuf[LINCAP];// 32 KB
  int t = threadIdx.x;

  if (blockIdx.x >= HB) {  // ---- hard-tail role: rows >= vbound ----
    size_t gid = (size_t)(blockIdx.x - HB) * HT + t;
    int row = vbound + (int)(gid >> 3);
    int q = (int)(gid & 7);
    if (row >= n) return;
    if (row < srow)
      nt_zero4(((float4*)out_feat) + (size_t)row * 8 + q);
    if (q == 0) {
      out_pos[(size_t)row * 3 + 0] = 0.f;
      out_pos[(size_t)row * 3 + 1] = 0.f;
      out_pos[(size_t)row * 3 + 2] = 0.f;
      out_valid[row] = 0.f;
    }
    return;
  }

  // ---- build role ----
  int b = blockIdx.x;
  if (b == 0 && t == 0) *sync = 0u;  // consumed by k_scan (next dispatch)
  for (int k = t; k < NBIN; k += HT) h[k] = 0u;
  __syncthreads();
  int chunk = (n + HB - 1) / HB;
  int i0 = b * chunk, i1 = min(n, i0 + chunk);
  int len = i1 - i0;
  float vs = vs_p[0];
  for (int j = t; j < len; j += HT) {
    size_t i = (size_t)(i0 + j);
    float x = pos[3 * i + 0];
    float y = pos[3 * i + 1];
    float z = pos[3 * i + 2];
    int lin = (int)floorf(x / vs) + STRIDE * (int)floorf(y / vs) +
              STRIDE * STRIDE * (int)floorf(z / vs);
    linbuf[j] = (uint32_t)lin;
    bytemap[lin] = 1;
    atomicAdd(&h[lin >> 9], 1u);  // LDS atomic
  }
  __syncthreads();
  // exclusive scan over h[4096] via wave shuffles (3 barriers, not 20)
  uint32_t v0 = h[t * 4 + 0], v1 = h[t * 4 + 1], v2 = h[t * 4 + 2], v3 = h[t * 4 + 3];
  uint32_t s3 = v0 + v1 + v2 + v3;
  uint32_t inc = s3;
  #pragma unroll
  for (int d = 1; d < 64; d <<= 1) {
    uint32_t o = __shfl_up(inc, d, 64);
    if ((t & 63) >= d) inc += o;
  }
  if ((t & 63) == 63) wsum[t >> 6] = inc;
  __syncthreads();
  if (t < 16) {
    uint32_t wv = wsum[t], wi = wv;
    #pragma unroll
    for (int d = 1; d < 16; d <<= 1) {
      uint32_t o = __shfl_up(wi, d, 16);
      if (t >= d) wi += o;
    }
    wsum[t] = wi - wv;  // exclusive wave offset
  }
  __syncthreads();
  uint32_t run = wsum[t >> 6] + (inc - s3);
  uint32_t* lr = &loff[(size_t)b * NBIN + t * 4];
  uint32_t c0 = run; lr[0] = run; run += v0;
  uint32_t c1 = run; lr[1] = run; run += v1;
  uint32_t c2 = run; lr[2] = run; run += v2;
  uint32_t c3 = run; lr[3] = run;
  __syncthreads();  // all v reads done -> safe to overwrite h with cursors
  h[t * 4 + 0] = (uint32_t)i0 + c0;
  h[t * 4 + 1] = (uint32_t)i0 + c1;
  h[t * 4 + 2] = (uint32_t)i0 + c2;
  h[t * 4 + 3] = (uint32_t)i0 + c3;
  __syncthreads();
  for (int j = t; j < len; j += HT) {
    int lin = (int)linbuf[j];
    uint32_t slot = atomicAdd(&h[lin >> 9], 1u);  // LDS atomic
    pairs[slot] = ((uint32_t)(lin & (BINVOX - 1)) << 21) | (uint32_t)(i0 + j);
  }
}

// 2: FUSED occupancy scan + descriptor transpose.
//    Blocks [0,NSEG): per-bin occupied count from bytemap (==1 exact) +
//    device-scope spin barrier -> occ_base, M.
//    Blocks [NSEG, NSEG+NTB): LDS-tiled transpose loff[c][bin] ->
//    offs_T[bin][c] = i0_c + loff[c][bin], with sentinel row offs_T[NBIN][c]
//    = end of chunk c, so k_pool reads contiguous 1KB descriptor rows.
__global__ __launch_bounds__(256) void k_scan(
    const uint32_t* __restrict__ bytemap_w, const uint32_t* __restrict__ loff,
    uint32_t* __restrict__ offs_T, uint32_t* __restrict__ occ_base,
    uint32_t* __restrict__ sync, uint32_t* __restrict__ seg_tot,
    uint32_t* __restrict__ Mp, int n) {
  int t = threadIdx.x;

  if (blockIdx.x >= NSEG) {  // ---- transpose role ----
    __shared__ uint32_t tile[256][65];  // 65: bank-conflict pad
    int tb = blockIdx.x - NSEG;         // 0..NTB-1, owns bins [tb*64, tb*64+64)
    int chunk = (n + HB - 1) / HB;
    uint32_t i0 = (uint32_t)(t * chunk);  // t = chunk index c
    const uint4* lp = (const uint4*)(loff + (size_t)t * NBIN + tb * 64);
    #pragma unroll
    for (int k = 0; k < 16; ++k) {
      uint4 v = lp[k];
      tile[t][k * 4 + 0] = i0 + v.x;
      tile[t][k * 4 + 1] = i0 + v.y;
      tile[t][k * 4 + 2] = i0 + v.z;
      tile[t][k * 4 + 3] = i0 + v.w;
    }
    __syncthreads();
    for (int j = 0; j < 64; ++j) {
      int bin = tb * 64 + j;
      offs_T[(size_t)bin * HB + t] = tile[t][j];  // 1KB coalesced per row
    }
    if (tb == NTB - 1)  // sentinel row: end of each chunk
      offs_T[(size_t)NBIN * HB + t] = (uint32_t)min(n, t * chunk + chunk);
    return;
  }

  // ---- occupancy-scan role ----
  __shared__ uint32_t s[SEGBINS];
  int b = blockIdx.x;
  int bin = b * SEGBINS + t;
  const uint4* bp = (const uint4*)bytemap_w + (size_t)bin * 32;  // 512 B
  uint32_t occ = 0;
  #pragma unroll
  for (int k = 0; k < 32; ++k) {
    uint4 v = bp[k];
    occ += cnt_eq1(v.x) + cnt_eq1(v.y) + cnt_eq1(v.z) + cnt_eq1(v.w);
  }
  s[t] = occ;
  __syncthreads();
  for (int off = 1; off < SEGBINS; off <<= 1) {
    uint32_t a = (t >= off) ? s[t - off] : 0u;
    __syncthreads();
    s[t] += a;
    __syncthreads();
  }
  uint32_t excl = s[t] - occ;
  if (t == 0) {
    __hip_atomic_store(&seg_tot[b], s[SEGBINS - 1], __ATOMIC_RELEASE,
                       __HIP_MEMORY_SCOPE_AGENT);
    __hip_atomic_fetch_add(sync, 1u, __ATOMIC_ACQ_REL, __HIP_MEMORY_SCOPE_AGENT);
    while (__hip_atomic_load(sync, __ATOMIC_ACQUIRE, __HIP_MEMORY_SCOPE_AGENT) <
           (uint32_t)NSEG) {}
  }
  __syncthreads();
  uint32_t pre = 0, grand = 0;
  #pragma unroll
  for (int i = 0; i < NSEG; ++i) {
    uint32_t v = __hip_atomic_load(&seg_tot[i], __ATOMIC_ACQUIRE,
                                   __HIP_MEMORY_SCOPE_AGENT);
    if (i < b) pre += v;
    grand += v;
  }
  occ_base[bin] = pre + excl;
  if (b == 0 && t == 0) Mp[0] = grand;
}

// 3: FUSED pool + soft-tail. Pool blocks: contiguous descriptor rows from
//    offs_T (2x 1KB), srcidx materialization, 8-tap float4 gather with
//    channel-rotation swizzle, LDS max-pool, contiguous output slab.
//    Tail blocks: zero rows [M, vbound) (NT feat stores).
__global__ __launch_bounds__(HT) void k_pool(
    const float* __restrict__ feat, const float* __restrict__ vs_p,
    const uint32_t* __restrict__ pairs, const uint32_t* __restrict__ offs_T,
    const uint32_t* __restrict__ occ_base, const uint8_t* __restrict__ bytemap,
    const uint32_t* __restrict__ Mp,
    float* __restrict__ out_pos, float* __restrict__ out_feat,
    float* __restrict__ out_valid, int n, int vbound) {
  __shared__ uint32_t smax[BINVOX * 32];  // 64 KB, phys idx vb*32+((ch+vb)&31)
  __shared__ u64 sbw[8];
  __shared__ uint32_t offs[HB], csum[HB];  // 2 KB
  __shared__ uint32_t srcidx[CAP];         // 6 KB
  int t = threadIdx.x;

  if (blockIdx.x >= NBIN) {  // ---- soft-tail role: rows [M, vbound) ----
    size_t gid = (size_t)(blockIdx.x - NBIN) * HT + t;
    int row = (int)(gid >> 3);
    int q = (int)(gid & 7);
    if (row >= vbound) return;
    uint32_t M = Mp[0];
    if ((uint32_t)row < M) return;
    nt_zero4(((float4*)out_feat) + (size_t)row * 8 + q);
    if (q == 0) {
      out_pos[(size_t)row * 3 + 0] = 0.f;
      out_pos[(size_t)row * 3 + 1] = 0.f;
      out_pos[(size_t)row * 3 + 2] = 0.f;
      out_valid[row] = 0.f;
    }
    return;
  }

  // ---- pool role ----
  int bin = blockIdx.x;
  #pragma unroll
  for (int k = 0; k < 16; ++k) smax[t + k * HT] = 0u;
  if (t < 512) {  // waves 0..7 exactly; ballot is wave-uniform
    uint32_t occb = bytemap[(size_t)bin * BINVOX + t];
    u64 m = __ballot(occb == 1u);
    if ((t & 63) == 0) sbw[t >> 6] = m;
  }
  if (t < HB) {  // contiguous descriptor rows: offs + next-bin (i0 cancels)
    uint32_t v0 = offs_T[(size_t)bin * HB + t];
    uint32_t v1 = offs_T[(size_t)(bin + 1) * HB + t];
    offs[t] = v0;
    csum[t] = v1 - v0;
  }
  __syncthreads();
  if (t < 64) {  // wave-0 inclusive scan of csum[256]
    uint32_t c0 = csum[t * 4], c1 = csum[t * 4 + 1];
    uint32_t c2 = csum[t * 4 + 2], c3 = csum[t * 4 + 3];
    uint32_t s1 = c0 + c1, s2 = s1 + c2, s3 = s2 + c3;
    uint32_t inc = s3;
    #pragma unroll
    for (int d = 1; d < 64; d <<= 1) {
      uint32_t o = __shfl_up(inc, d, 64);
      if (t >= d) inc += o;
    }
    uint32_t base = inc - s3;
    csum[t * 4]     = base + c0;
    csum[t * 4 + 1] = base + s1;
    csum[t * 4 + 2] = base + s2;
    csum[t * 4 + 3] = base + s3;
  }
  __syncthreads();
  uint32_t cnt = csum[HB - 1];
  if (cnt == 0) return;  // block-uniform

  bool fits = (cnt <= (uint32_t)CAP);  // block-uniform
  if (fits) {
    if (t < HB) {
      uint32_t beg = t ? csum[t - 1] : 0u;
      uint32_t len = csum[t] - beg;
      uint32_t o = offs[t];
      for (uint32_t j = 0; j < len; ++j) srcidx[beg + j] = o + j;
    }
    __syncthreads();
  }

  int g = t >> 3;    // point slot 0..127
  int q = t & 7;     // float4 chunk (channels q*4..q*4+3)
  const float4* f4 = (const float4*)feat;
  uint32_t last = cnt - 1;
  for (uint32_t u = (uint32_t)g; u < cnt; u += 1024) {
    uint32_t pp[8];
    #pragma unroll
    for (int k = 0; k < 8; ++k) {
      uint32_t uu = min(u + 128u * k, last);
      uint32_t s = fits ? srcidx[uu] : src_of(uu, csum, offs);
      pp[k] = pairs[s];
    }
    float4 vv[8];
    #pragma unroll
    for (int k = 0; k < 8; ++k)
      vv[k] = f4[(size_t)(pp[k] & 0x1FFFFFu) * 8 + q];
    #pragma unroll
    for (int k = 0; k < 8; ++k) {
      uint32_t vb = pp[k] >> 21;
      uint32_t* sb = &smax[vb * 32];
      uint32_t c = (uint32_t)q * 4 + vb;  // rotation: phys ch = (ch+vb)&31
      atomicMax(&sb[(c + 0) & 31], enc_f32(vv[k].x));
      atomicMax(&sb[(c + 1) & 31], enc_f32(vv[k].y));
      atomicMax(&sb[(c + 2) & 31], enc_f32(vv[k].z));
      atomicMax(&sb[(c + 3) & 31], enc_f32(vv[k].w));
    }
  }
  __syncthreads();

  int vb = t >> 1, half = t & 1;
  u64 w = sbw[vb >> 6];
  int bit = vb & 63;
  if ((w >> bit) & 1ull) {
    uint32_t lr = (uint32_t)__popcll(w & ((1ull << bit) - 1ull));
    for (int ww = 0; ww < (vb >> 6); ++ww) lr += (uint32_t)__popcll(sbw[ww]);
    uint32_t rank = occ_base[bin] + lr;
    float4* orow = (float4*)(out_feat + (size_t)rank * 32 + half * 16);
    const uint32_t* sb = &smax[vb * 32];
    #pragma unroll
    for (int j = 0; j < 4; ++j) {
      uint32_t c = (uint32_t)half * 16 + j * 4 + vb;  // un-rotate
      float4 o;
      o.x = dec_f32(sb[(c + 0) & 31]);
      o.y = dec_f32(sb[(c + 1) & 31]);
      o.z = dec_f32(sb[(c + 2) & 31]);
      o.w = dec_f32(sb[(c + 3) & 31]);
      orow[j] = o;
    }
    if (half == 0) {
      float vs = vs_p[0];
      int lin = bin * BINVOX + vb;
      int cx = lin & 127, cy = (lin >> 7) & 127, cz = lin >> 14;
      out_pos[(size_t)rank * 3 + 0] = ((float)cx + 0.5f) * vs;
      out_pos[(size_t)rank * 3 + 1] = ((float)cy + 0.5f) * vs;
      out_pos[(size_t)rank * 3 + 2] = ((float)cz + 0.5f) * vs;
      out_valid[rank] = 1.0f;
    }
  }
}

// 4 (out-tail fallback only): wipe the scratch region (feat rows >= srow)
__global__ void k_tail2(float4* __restrict__ dst, long long cnt4) {
  long long i = (long long)blockIdx.x * blockDim.x + threadIdx.x;
  if (i < cnt4) nt_zero4(dst + i);
}

extern "C" void kernel_launch(void* const* d_in, const int* in_sizes, int n_in,
                              void* d_out, int out_size, void* d_ws, size_t ws_size,
                              hipStream_t stream) {
  const float* pos  = (const float*)d_in[0];
  const float* feat = (const float*)d_in[1];
  const float* vs   = (const float*)d_in[2];
  int n = in_sizes[0] / 3;  // 2,000,000

  float*    out_pos   = (float*)d_out;
  uint32_t* out_feat  = (uint32_t*)(out_pos + (size_t)n * 3);
  float*    out_valid = (float*)((float*)out_feat + (size_t)n * 32);

  // vs = 1.0 in this problem -> coords 0..99 -> M <= 100^3 = 1e6 voxels.
  // (The reference's STRIDE=128 lin-packing itself requires coords < 128.)
  int vbound = n < 1000000 ? n : 1000000;

  // Scratch: pairs(n) | loff[HB][NBIN] | offs_T[(NBIN+1)][HB] | occ_base(NBIN)
  // | bytemap(NVOX B). ~18.5 MB. Prefer d_ws; else output-tail rows >= srow
  // (> vbound; pool writes rows < M <= vbound; hard-tail stops at srow;
  // k_tail2 wipes after). bytemap never assumed-zero (consumers test ==1).
  size_t scratch_u32 = (size_t)n + (size_t)HB * NBIN + (size_t)(NBIN + 1) * HB +
                       NBIN + NVOX / 4;
  size_t ws_need = 256 + scratch_u32 * 4;

  uint32_t* Mp      = (uint32_t*)d_ws;
  uint32_t* sync    = Mp + 1;
  uint32_t* seg_tot = Mp + 8;  // NSEG u32

  uint32_t* base;
  int srow;
  if (ws_size >= ws_need) {
    base = (uint32_t*)((char*)d_ws + 256);
    srow = n;
  } else {
    base = out_feat + (size_t)n * 32 - scratch_u32;
    srow = (int)(((size_t)n * 32 - scratch_u32) / 32);
  }
  uint32_t* pairs    = base;
  uint32_t* loff     = pairs + n;                    // HB*NBIN
  uint32_t* offs_T   = loff + (size_t)HB * NBIN;     // (NBIN+1)*HB
  uint32_t* occ_base = offs_T + (size_t)(NBIN + 1) * HB;  // NBIN
  uint8_t*  bytemap  = (uint8_t*)(occ_base + NBIN);  // NVOX bytes

  int hard_blocks = (int)(((size_t)(n - vbound) * 8 + HT - 1) / HT);
  k_build<<<HB + hard_blocks, HT, 0, stream>>>(
      pos, vs, bytemap, loff, pairs, sync, out_pos, (float*)out_feat,
      out_valid, n, vbound, srow);
  k_scan<<<NSEG + NTB, 256, 0, stream>>>((const uint32_t*)bytemap, loff,
                                         offs_T, occ_base, sync, seg_tot, Mp, n);
  int soft_blocks = (int)(((size_t)vbound * 8 + HT - 1) / HT);
  k_pool<<<NBIN + soft_blocks, HT, 0, stream>>>(
      feat, vs, pairs, offs_T, occ_base, bytemap, Mp,
      out_pos, (float*)out_feat, out_valid, n, vbound);
  if (srow < n) {
    long long cnt4 = ((long long)n * 32 - (long long)srow * 32) / 4;
    k_tail2<<<(int)((cnt4 + 1023) / 1024), 1024, 0, stream>>>(
        (float4*)(out_feat + (size_t)srow * 32), cnt4);
  }
}